// Round 11
// baseline (3859.830 us; speedup 1.0000x reference)
//
#include <hip/hip_runtime.h>
#include <hip/hip_fp16.h>
#include <stdint.h>

#define TT 1024
#define BB 64
#define DHH 256
#define HH 512
#define G3 1536
#define CHK 256   // f16 per (g,jsl) exchange chunk: [16 batches][16 j] — ONE constant for store/poll/reader

typedef _Float16 f16;
typedef _Float16 f16x4 __attribute__((ext_vector_type(4)));
typedef _Float16 f16x8 __attribute__((ext_vector_type(8)));
typedef float f32x4 __attribute__((ext_vector_type(4)));
typedef unsigned long long u64;

__device__ __forceinline__ float sigm(float x){ return 1.0f/(1.0f+__expf(-x)); }
__device__ __forceinline__ float tanh_f(float x){ return 2.0f/(1.0f+__expf(-2.0f*x)) - 1.0f; }

// ---------------- prep: f32->f16 weights, folded bias ----------------
__global__ void k_prep(const float* __restrict__ wih, const float* __restrict__ whh,
                       const float* __restrict__ bih, const float* __restrict__ bhh,
                       f16* __restrict__ wih_h, f16* __restrict__ whh_h, float* __restrict__ biasf){
  int i = blockIdx.x*256 + threadIdx.x;
  if (i < G3*HH){ wih_h[i] = (f16)wih[i]; whh_h[i] = (f16)whh[i]; }
  if (i < G3) biasf[i] = bih[i] + (i < 2*HH ? bhh[i] : 0.0f);
}

// ---------------- build x = concat(s, p.sum(axis=2)) as f16 [T*B][512] ----------------
__global__ void k_buildx(const float* __restrict__ s, const float* __restrict__ p, f16* __restrict__ x){
  int m = blockIdx.x;             // m = t*64 + b
  int t = m >> 6, b = m & 63;
  int l = threadIdx.x;            // 0..63 -> 4 floats each
  const float4* s4 = reinterpret_cast<const float4*>(s + ((size_t)b*TT + t)*DHH);
  const float4* p4 = reinterpret_cast<const float4*>(p + ((size_t)b*TT + t)*8*DHH);
  float4 sv = s4[l];
  float4 a  = p4[l];
#pragma unroll
  for (int k=1;k<8;k++){ float4 v = p4[k*64 + l]; a.x+=v.x; a.y+=v.y; a.z+=v.z; a.w+=v.w; }
  f16* xr = x + (size_t)m*HH;
  f16x4 hs = { (f16)sv.x,(f16)sv.y,(f16)sv.z,(f16)sv.w };
  f16x4 hp = { (f16)a.x,(f16)a.y,(f16)a.z,(f16)a.w };
  *reinterpret_cast<f16x4*>(xr + l*4)       = hs;
  *reinterpret_cast<f16x4*>(xr + 256 + l*4) = hp;
}

// ---------------- gi GEMM (round-8 validated layout) ----------------
// gi[((t*16+ksl)*4+g)*16 + b'][96] f16, 96 = gate*32 + j'
#define LDAP 72
__global__ __launch_bounds__(256) void k_gemm(const f16* __restrict__ x, const f16* __restrict__ w,
                       const float* __restrict__ biasf, f16* __restrict__ gi){
  __shared__ f16 lA[128*LDAP];
  __shared__ f16 lB[128*LDAP];
  int by = blockIdx.x;           // wrow tile (12)
  int bx = blockIdx.y;           // xrow tile (512)
  int tid = threadIdx.x, l = tid & 63, wv = tid >> 6;
  int wm = wv >> 1, wn = wv & 1;

  f32x4 acc[4][4];
#pragma unroll
  for (int i=0;i<4;i++)
#pragma unroll
    for (int j=0;j<4;j++) acc[i][j] = (f32x4){0.f,0.f,0.f,0.f};

  for (int kt = 0; kt < 8; ++kt){
#pragma unroll
    for (int r = 0; r < 4; ++r){
      int c = tid + 256*r;
      int row = c >> 3, o = c & 7;
      f16x8 va = *reinterpret_cast<const f16x8*>(w + (size_t)(by*128+row)*HH + kt*64 + o*8);
      f16x8 vb = *reinterpret_cast<const f16x8*>(x + (size_t)(bx*128+row)*HH + kt*64 + o*8);
      *reinterpret_cast<f16x8*>(&lA[row*LDAP + o*8]) = va;
      *reinterpret_cast<f16x8*>(&lB[row*LDAP + o*8]) = vb;
    }
    __syncthreads();
#pragma unroll
    for (int kk = 0; kk < 2; ++kk){
      f16x8 aF[4], bF[4];
#pragma unroll
      for (int mi=0;mi<4;mi++)
        aF[mi] = *reinterpret_cast<const f16x8*>(&lA[(wm*64+mi*16+(l&15))*LDAP + kk*32 + (l>>4)*8]);
#pragma unroll
      for (int ni=0;ni<4;ni++)
        bF[ni] = *reinterpret_cast<const f16x8*>(&lB[(wn*64+ni*16+(l&15))*LDAP + kk*32 + (l>>4)*8]);
#pragma unroll
      for (int mi=0;mi<4;mi++)
#pragma unroll
        for (int ni=0;ni<4;ni++)
          acc[mi][ni] = __builtin_amdgcn_mfma_f32_16x16x32_f16(aF[mi], bF[ni], acc[mi][ni], 0,0,0);
    }
    __syncthreads();
  }
#pragma unroll
  for (int mi=0;mi<4;mi++){
    int wrow0 = by*128 + wm*64 + mi*16 + (l>>4)*4;
    float4 bv = *reinterpret_cast<const float4*>(biasf + wrow0);
    int gate = wrow0 >> 9, j = wrow0 & 511, ksl = j >> 5, rp = gate*32 + (j&31);
#pragma unroll
    for (int ni=0;ni<4;ni++){
      int xrow = bx*128 + wn*64 + ni*16 + (l&15);
      int t = xrow >> 6, g = (xrow>>4)&3, bp = xrow & 15;
      size_t dst = ((((size_t)t*16 + ksl)*4 + g)*16 + bp)*96 + rp;
      union { u64 u; f16x4 h; } cv;
      cv.h = (f16x4){ (f16)(acc[mi][ni][0]+bv.x), (f16)(acc[mi][ni][1]+bv.y),
                      (f16)(acc[mi][ni][2]+bv.z), (f16)(acc[mi][ni][3]+bv.w) };
      *reinterpret_cast<u64*>(gi + dst) = cv.u;
    }
  }
}

// ---------------- persistent GRU scan: 2-way group-multiplexed MALL exchange ----------------
// 64 single-wave WGs: set st = bid&1 -> groups {2st, 2st+1}; jsl = bid>>1 (16 j, 48 W rows in
// AGPRs, SHARED by both groups — same weights). Each wave alternates phases A/B: consume own
// group's h(t-1) (polled ONE PHASE EARLIER -> publish latency + load RT already elapsed, first
// check usually hits), early-issue the other group's poll, MFMA+gates, publish. Latency of the
// MALL round-trip is hidden under the other group's compute. Barrier-free, LDS-free: the chunked
// h layout makes each lane's 16B poll loads exactly its MFMA B-fragments (no staging).
// Poll-the-data (proven r3-8): hh poisoned 0xFF; finite h never yields f16 0xFFFF; each u64 is
// one relaxed agent-atomic store (all-or-nothing); retry loops guarantee progress (pure dataflow).
__global__ __launch_bounds__(64, 1) void k_scan(const f16* __restrict__ whh_h, const f16* __restrict__ gi,
                      const float* __restrict__ bhh, f16* __restrict__ hh){
  const int bid = blockIdx.x;                       // 0..63
  const int st = bid & 1, jsl = bid >> 1;           // set, j-slice 0..31
  const int gA = st*2, gB = st*2 + 1;
  const int l = threadIdx.x, lm = l & 15, lh = l >> 4;

  // persistent A-fragments: aW[gate][kt], W row = gate*512 + jsl*16 + lm, k = kt*32 + lh*8
  f16x8 aW[3][16];
#pragma unroll
  for (int gate = 0; gate < 3; ++gate){
    const f16* wr = whh_h + ((size_t)gate*512 + jsl*16 + lm)*HH + lh*8;
#pragma unroll
    for (int kt = 0; kt < 16; ++kt)
      aW[gate][kt] = *reinterpret_cast<const f16x8*>(wr + kt*32);
  }
#pragma unroll
  for (int gate = 0; gate < 3; ++gate)
#pragma unroll
    for (int kt = 0; kt < 16; ++kt)
      asm volatile("" : "+a"(aW[gate][kt]));        // pin W in AGPRs (no remat, no spill)

  float4 bnv = *reinterpret_cast<const float4*>(bhh + 2*HH + jsl*16 + lh*4);
  float bna[4] = {bnv.x, bnv.y, bnv.z, bnv.w};
  const int ksl2 = jsl >> 1, jo = (jsl & 1)*16 + lh*4;          // gi addressing (r8-validated)
  const int lbo8 = (lh>>1)*64 + lm*4 + (lh&1)*2;                // lane u64 offset in group region
  const size_t pofs = (size_t)lm*16 + lh*4;                     // producer f16 offset in chunk

  union U64H { u64 u; f16x4 h; };
  union BFR  { u64 q[2]; f16x8 v8; };
  BFR  qA[16], qB[16];
  U64H cAA[3], cAB[3], cAC[3], hoA, hnA;
  U64H cBA[3], cBB[3], cBC[3], hoB, hnB;
  hoA.u = 0ull; hoB.u = 0ull;

#define GLOAD(G_, T_, DST) {                                                                  \
    const f16* gb_ = gi + ((((size_t)(T_)*16 + ksl2)*4 + (G_))*16 + lm)*96;                   \
    DST[0].u = *reinterpret_cast<const u64*>(gb_ + jo);                                       \
    DST[1].u = *reinterpret_cast<const u64*>(gb_ + 32 + jo);                                  \
    DST[2].u = *reinterpret_cast<const u64*>(gb_ + 64 + jo); }

#define PISSUE(Q, G_, TM1) {                                                                  \
    const u64* hb_ = reinterpret_cast<const u64*>(hh)                                         \
                   + ((size_t)(TM1)*4 + (G_))*(32*CHK/4) + lbo8;                              \
    _Pragma("unroll")                                                                         \
    for (int kt = 0; kt < 16; ++kt){                                                          \
      Q[kt].q[0] = __hip_atomic_load(hb_ + kt*128,     __ATOMIC_RELAXED, __HIP_MEMORY_SCOPE_AGENT); \
      Q[kt].q[1] = __hip_atomic_load(hb_ + kt*128 + 1, __ATOMIC_RELAXED, __HIP_MEMORY_SCOPE_AGENT); } }

#define PCHECK(Q, OKV) { OKV = 1;                                                             \
    _Pragma("unroll")                                                                         \
    for (int kt = 0; kt < 16; ++kt){                                                          \
      OKV &= (int)((unsigned)Q[kt].q[0] != 0xFFFFFFFFu);                                      \
      OKV &= (int)((unsigned)Q[kt].q[1] != 0xFFFFFFFFu); } }

#define PUBLISH(G_, T_, HN)                                                                   \
    __hip_atomic_store(reinterpret_cast<u64*>(hh + (((size_t)(T_)*4 + (G_))*32 + jsl)*CHK + pofs), \
                       HN.u, __ATOMIC_RELAXED, __HIP_MEMORY_SCOPE_AGENT);

  // ---- t = 0 peel: h_{-1}=0 for both groups; fill gi pipelines; pre-issue qA ----
  {
    GLOAD(gA, 0, cAA) GLOAD(gA, 1, cAB) GLOAD(gA, 2, cAC)
    GLOAD(gB, 0, cBA) GLOAD(gB, 1, cBB) GLOAD(gB, 2, cBC)
#pragma unroll
    for (int r = 0; r < 4; ++r){
      float rg = sigm((float)cAA[0].h[r]);
      float zg = sigm((float)cAA[1].h[r]);
      float ng = tanh_f((float)cAA[2].h[r] + rg*bna[r]);
      hnA.h[r] = (f16)((1.0f - zg)*ng);
    }
    hoA.u = hnA.u; PUBLISH(gA, 0, hnA)
#pragma unroll
    for (int r = 0; r < 4; ++r){
      float rg = sigm((float)cBA[0].h[r]);
      float zg = sigm((float)cBA[1].h[r]);
      float ng = tanh_f((float)cBA[2].h[r] + rg*bna[r]);
      hnB.h[r] = (f16)((1.0f - zg)*ng);
    }
    hoB.u = hnB.u; PUBLISH(gB, 0, hnB)
    PISSUE(qA, gA, 0)
  }

  // PHASE: consume QTHIS = h_G(T-1); sync-retry if poison; early-issue QOTH (other group's
  // poll for step TOTH data); gi(T+2) prefetch; MFMA; gates; publish h_G(T).
#define PHASE(G_, T_, QTHIS, QOTH, GOTH, TOTH, CUR, NXT2, HO, HN)                             \
  {                                                                                           \
    int ok_;                                                                                  \
    PCHECK(QTHIS, ok_)                                                                        \
    while (!__all(ok_)){ PISSUE(QTHIS, G_, (T_)-1) PCHECK(QTHIS, ok_) }                       \
    PISSUE(QOTH, GOTH, TOTH)                                                                  \
    { const int tn_ = ((T_)+2 < TT) ? (T_)+2 : TT-1; GLOAD(G_, tn_, NXT2) }                   \
    f32x4 aR = (f32x4){0.f,0.f,0.f,0.f};                                                      \
    f32x4 aZ = (f32x4){0.f,0.f,0.f,0.f};                                                      \
    f32x4 aN = (f32x4){0.f,0.f,0.f,0.f};                                                      \
    _Pragma("unroll")                                                                         \
    for (int kt = 0; kt < 16; ++kt){                                                          \
      aR = __builtin_amdgcn_mfma_f32_16x16x32_f16(aW[0][kt], QTHIS[kt].v8, aR, 0,0,0);        \
      aZ = __builtin_amdgcn_mfma_f32_16x16x32_f16(aW[1][kt], QTHIS[kt].v8, aZ, 0,0,0);        \
      aN = __builtin_amdgcn_mfma_f32_16x16x32_f16(aW[2][kt], QTHIS[kt].v8, aN, 0,0,0);        \
    }                                                                                         \
    _Pragma("unroll")                                                                         \
    for (int r = 0; r < 4; ++r){                                                              \
      float rg = sigm((float)CUR[0].h[r] + aR[r]);                                            \
      float zg = sigm((float)CUR[1].h[r] + aZ[r]);                                            \
      float ng = tanh_f((float)CUR[2].h[r] + rg*(aN[r] + bna[r]));                            \
      HN.h[r] = (f16)((1.0f - zg)*ng + zg*(float)HO.h[r]);                                    \
    }                                                                                         \
    HO.u = HN.u;                                                                              \
    PUBLISH(G_, T_, HN)                                                                       \
  }

  // t = 1..1023 in 341 triples; per group 3-buffer gi rotation; phases interleaved A,B
  for (int t = 1; t < TT; t += 3){
    PHASE(gA, t,   qA, qB, gB, t-1, cAB, cAA, hoA, hnA)
    PHASE(gB, t,   qB, qA, gA, t,   cBB, cBA, hoB, hnB)
    PHASE(gA, t+1, qA, qB, gB, t,   cAC, cAB, hoA, hnA)
    PHASE(gB, t+1, qB, qA, gA, t+1, cBC, cBB, hoB, hnB)
    PHASE(gA, t+2, qA, qB, gB, t+1, cAA, cAC, hoA, hnA)
    PHASE(gB, t+2, qB, qA, gA, t+2, cBA, cBC, hoB, hnB)
  }
#undef PHASE
#undef GLOAD
#undef PISSUE
#undef PCHECK
#undef PUBLISH
}

// ---------------- rewards = sigmoid(h @ W_t + b_t) (chunked hh layout, stride CHK) ----------------
__global__ void k_reward(const f16* __restrict__ hh, const float* __restrict__ wt,
                         const float* __restrict__ bt, float* __restrict__ out){
  int wv = threadIdx.x >> 6, l = threadIdx.x & 63;
  int idx = blockIdx.x*4 + wv;          // idx = b*1024 + t (output order [B][T])
  int b = idx >> 10, t = idx & 1023;
  int g = b >> 4, bl = b & 15;
  const f16* hr = hh + (((size_t)t*4 + g)*32 + (l >> 1))*CHK + bl*16 + (l & 1)*8;
  f16x8 hv = *reinterpret_cast<const f16x8*>(hr);
  float4 w0 = *reinterpret_cast<const float4*>(wt + l*8);
  float4 w1 = *reinterpret_cast<const float4*>(wt + l*8 + 4);
  float sum = (float)hv[0]*w0.x + (float)hv[1]*w0.y + (float)hv[2]*w0.z + (float)hv[3]*w0.w
            + (float)hv[4]*w1.x + (float)hv[5]*w1.y + (float)hv[6]*w1.z + (float)hv[7]*w1.w;
#pragma unroll
  for (int m=32;m>=1;m>>=1) sum += __shfl_xor(sum, m);
  if (l==0) out[idx] = sigm(sum + bt[0]);
}

extern "C" void kernel_launch(void* const* d_in, const int* in_sizes, int n_in,
                              void* d_out, int out_size, void* d_ws, size_t ws_size,
                              hipStream_t stream) {
  const float* s   = (const float*)d_in[0];
  const float* p   = (const float*)d_in[1];
  const float* wih = (const float*)d_in[2];
  const float* whh = (const float*)d_in[3];
  const float* bih = (const float*)d_in[4];
  const float* bhh = (const float*)d_in[5];
  const float* wt  = (const float*)d_in[6];
  const float* bt  = (const float*)d_in[7];
  float* out = (float*)d_out;

  char* ws = (char*)d_ws;
  size_t o = 0;
  auto take = [&](size_t bytes)->char*{ char* r = ws + o; o = (o + bytes + 255) & ~(size_t)255; return r; };
  f16*      x_h   = (f16*)   take((size_t)TT*BB*HH*2);       // 67 MB
  f16*      wih_h = (f16*)   take((size_t)G3*HH*2);
  f16*      whh_h = (f16*)   take((size_t)G3*HH*2);
  float*    biasf = (float*) take((size_t)G3*4);
  f16*      gi_s  = (f16*)   take((size_t)TT*BB*G3*2);       // 201 MB
  f16*      hh    = (f16*)   take((size_t)TT*BB*HH*2);       // 67 MB, chunked layout
  (void)ws_size; (void)in_sizes; (void)n_in; (void)out_size;

  hipMemsetAsync(hh, 0xFF, (size_t)TT*BB*HH*2, stream);      // poison: poll-the-data sentinel
  k_prep  <<<3072, 256, 0, stream>>>(wih, whh, bih, bhh, wih_h, whh_h, biasf);
  k_buildx<<<TT*BB, 64, 0, stream>>>(s, p, x_h);
  k_gemm  <<<dim3(12, 512), 256, 0, stream>>>(x_h, wih_h, biasf, gi_s);
  k_scan  <<<64, 64, 0, stream>>>(whh_h, gi_s, bhh, hh);
  k_reward<<<TT*BB/4, 256, 0, stream>>>(hh, wt, bt, out);
}